// Round 15
// baseline (2403.925 us; speedup 1.0000x reference)
//
#include <hip/hip_runtime.h>
#include <hip/hip_bf16.h>

typedef __hip_bfloat16 bf16;
typedef unsigned short u16;
typedef __attribute__((ext_vector_type(8))) short s16x8;   // 8 bf16 (4 VGPRs) MFMA frag
typedef __attribute__((ext_vector_type(4))) float f32x4;   // MFMA accumulator

#define B_ 512
#define T_ 150
#define S_ 151
#define D_ 256
#define H_ 8
#define HD_ 32
#define FF_ 1024
#define NC_ 4
#define DEPTH_ 6
#define MTOT 77312            // B_*S_ = 128 * 604 = 64 * 1208
#define MT128 (MTOT / 128)    // 604
#define MT64 (MTOT / 64)      // 1208

// bf16 workspace regions (elements):
#define XOFF 0
#define C1OFF (MTOT * D_)               // x: MTOT*256
#define C2OFF (C1OFF + MTOT * FF_)      // c1: MTOT*1024 (qkv out)
#define WSELEMS (C2OFF + MTOT * D_)     // c2: MTOT*256 (attn out, tiled)

// Transposed bf16 weights Wt[N][K], all layers, rebuilt per call:
#define QKVT_OFF 0
#define OUTT_OFF (QKVT_OFF + DEPTH_ * D_ * 768)
#define FFN1T_OFF (OUTT_OFF + DEPTH_ * D_ * D_)
#define FFN2T_OFF (FFN1T_OFF + DEPTH_ * D_ * FF_)
#define WTELEMS (FFN2T_OFF + DEPTH_ * FF_ * D_)    // 9.4 MB

// Static device memory (d_ws proved unusable rounds 1-3).
__device__ __align__(16) u16 g_ws[WSELEMS];
__device__ __align__(16) u16 g_wt[WTELEMS];
__device__ int g_f32flag;   // 1 => external buffers f32, 0 => bf16

__device__ __forceinline__ float ldf(const void* p, size_t i, int f) {
  return f ? ((const float*)p)[i] : __bfloat162float(((const bf16*)p)[i]);
}
__device__ __forceinline__ float b2f(u16 u) {
  union { unsigned int i; float f; } v; v.i = ((unsigned int)u) << 16; return v.f;
}
__device__ __forceinline__ u16 f2b(float x) {
  bf16 h = __float2bfloat16(x);
  return *reinterpret_cast<u16*>(&h);
}

// Async global->LDS, 16 B/lane. LDS dest = wave-uniform base + lane*16.
typedef __attribute__((address_space(3))) void lds_void;
typedef const __attribute__((address_space(1))) void glob_void;
__device__ __forceinline__ void gload_lds16(const u16* g, u16* l) {
  __builtin_amdgcn_global_load_lds((glob_void*)g, (lds_void*)l, 16, 0, 0);
}

// ---------------------------------------------------------------------------
// Dtype probe on pos_embed (38656 elems ~N(0,0.02^2)) viewed as 16-bit words.
// ---------------------------------------------------------------------------
#define PROBE_N 38656
__global__ __launch_bounds__(256) void probe_kernel(const void* pe)
{
  const u16* w = (const u16*)pe;
  int susp = 0, zeroEven = 0;
  for (int k = threadIdx.x; k < PROBE_N; k += 256) {
    u16 u = w[k];
    int ex = (u >> 7) & 0xFF;
    if (ex >= 141) susp++;
    if ((k & 1) == 0 && (u & 0x7FFF) == 0) zeroEven++;
  }
  __shared__ int s_susp, s_zero;
  if (threadIdx.x == 0) { s_susp = 0; s_zero = 0; }
  __syncthreads();
  atomicAdd(&s_susp, susp);
  atomicAdd(&s_zero, zeroEven);
  __syncthreads();
  if (threadIdx.x == 0)
    g_f32flag = (s_susp > 0 || s_zero >= ((PROBE_N / 2) * 9) / 10) ? 1 : 0;
}

// ---------------------------------------------------------------------------
// Weight transpose+convert: Wt[l][n][k] = W[l][k][n] as bf16.
// ---------------------------------------------------------------------------
__global__ __launch_bounds__(256) void wtrans_kernel(const void* src, int dstOff,
                                                     int K, int N, int total)
{
  const int f = g_f32flag;
  int idx = blockIdx.x * 256 + threadIdx.x;
  if (idx >= total) return;
  int kn = K * N;
  int l = idx / kn;
  int r = idx - l * kn;
  int k = r / N;
  int n = r - k * N;
  g_wt[dstOff + (size_t)l * kn + (size_t)n * K + k] = f2b(ldf(src, idx, f));
}

// ---------------------------------------------------------------------------
// Embedding: row = blockIdx.x, writes bf16 x.
// ---------------------------------------------------------------------------
__global__ __launch_bounds__(256) void embed_kernel(
    const int* __restrict__ tt, const int* __restrict__ dids,
    const void* av, const void* dv, const void* vv,
    const void* aW, const void* ab, const void* dW, const void* db,
    const void* vW, const void* vb, const void* table, const void* pos,
    const void* cls)
{
  const int f = g_f32flag;
  u16* x = g_ws + XOFF;
  int row = blockIdx.x;
  int d = threadIdx.x;
  int b = row / S_;
  int s = row - b * S_;
  float val;
  if (s == 0) {
    val = ldf(cls, d, f);
  } else {
    int t = s - 1;
    int idx = b * T_ + t;
    int ty = tt[idx];
    if (ty == 0) {
      val = ldf(av, idx, f) * ldf(aW, d, f) + ldf(ab, d, f);
    } else if (ty == 1) {
      float acc = ldf(db, d, f) + ldf(vb, d, f);
#pragma unroll
      for (int i = 0; i < 10; i++) acc += ldf(dv, (size_t)idx * 10 + i, f) * ldf(dW, i * D_ + d, f);
#pragma unroll
      for (int i = 0; i < 3; i++) acc += ldf(vv, (size_t)idx * 3 + i, f) * ldf(vW, i * D_ + d, f);
      val = acc;
    } else if (ty == 2) {
      int did = dids[idx] & (NC_ - 1);
      val = ldf(table, (size_t)did * D_ + d, f);
    } else {
      val = 0.f;
    }
  }
  val += ldf(pos, s * D_ + d, f);
  x[(size_t)row * D_ + d] = f2b(val);
}

// ---------------------------------------------------------------------------
// MFMA GEMM (round-9 proven): 128x128, BK=64, 256 thr, global_load_lds w=16,
// xor-swizzled chunks (0 conflicts), XCD swizzle, LDS-staged epilogue.
// Used for qkv only (tiledC=0). UNCHANGED.
// ---------------------------------------------------------------------------
__global__ __launch_bounds__(256, 3) void gemm_mfma(
    int aOff, int wtOff, const void* bias, size_t bOff,
    int cOff, int N, int K, int relu, int NB, int tiledC)
{
  const int f = g_f32flag;
  const u16* A = g_ws + aOff;
  const u16* Bt = g_wt + wtOff;
  u16* C = g_ws + cOff;
  __shared__ __align__(16) u16 sm[16384];
  const int tid = threadIdx.x;

  int gblk = blockIdx.x;
  int bm, bn;
  {
    const int full = (MT128 / 8) * 8;        // 600
    if (gblk < NB * full) {
      int per = NB * 8;
      int grp = gblk / per, rem = gblk % per;
      bm = grp * 8 + (rem & 7);
      bn = rem >> 3;
    } else {
      int id = gblk - NB * full;
      bm = full + id / NB;
      bn = id % NB;
    }
  }

  const int lane = tid & 63, wid = tid >> 6;
  const int wm = (wid >> 1) * 64, wn = (wid & 1) * 64;
  const int frow = lane & 15, quad = lane >> 4;

  const int rg = lane >> 3;
  const int ck = ((lane & 7) ^ rg) * 8;
  const u16* Ag[4]; const u16* Bg[4];
  u16 *Asl[4], *Bsl[4];
#pragma unroll
  for (int p = 0; p < 4; p++) {
    int grp = wid * 4 + p;
    int row = grp * 8 + rg;
    Ag[p] = A + (size_t)(bm * 128 + row) * K + ck;
    Bg[p] = Bt + (size_t)(bn * 128 + row) * K + ck;
    Asl[p] = &sm[grp * 512];
    Bsl[p] = &sm[8192 + grp * 512];
  }

  f32x4 acc[4][4] = {};

  for (int kt = 0; kt < K; kt += 64) {
    if (kt) __syncthreads();
#pragma unroll
    for (int p = 0; p < 4; p++) {
      gload_lds16(Ag[p] + kt, Asl[p]);
      gload_lds16(Bg[p] + kt, Bsl[p]);
    }
    __syncthreads();
#pragma unroll
    for (int s = 0; s < 2; s++) {
      s16x8 af[4], bfr[4];
      const int cfr = ((s * 4 + quad) ^ (frow & 7)) * 8;
#pragma unroll
      for (int t = 0; t < 4; t++) {
        af[t]  = *(const s16x8*)&sm[(wm + t * 16 + frow) * 64 + cfr];
        bfr[t] = *(const s16x8*)&sm[8192 + (wn + t * 16 + frow) * 64 + cfr];
      }
#pragma unroll
      for (int mt = 0; mt < 4; mt++)
#pragma unroll
        for (int nt = 0; nt < 4; nt++)
          acc[mt][nt] = __builtin_amdgcn_mfma_f32_16x16x32_bf16(af[mt], bfr[nt], acc[mt][nt], 0, 0, 0);
    }
  }

  float bv[4];
#pragma unroll
  for (int nt = 0; nt < 4; nt++)
    bv[nt] = ldf(bias, bOff + (size_t)(bn * 128 + wn + nt * 16 + frow), f);
  __syncthreads();
#pragma unroll
  for (int p = 0; p < 2; p++) {
    if ((wid >> 1) == p) {
#pragma unroll
      for (int mt = 0; mt < 4; mt++)
#pragma unroll
        for (int nt = 0; nt < 4; nt++)
#pragma unroll
          for (int r = 0; r < 4; r++) {
            int rl = (wm & 63) + mt * 16 + quad * 4 + r;
            float v = acc[mt][nt][r] + bv[nt];
            if (relu) v = fmaxf(v, 0.f);
            sm[rl * 136 + wn + nt * 16 + frow] = f2b(v);
          }
    }
    __syncthreads();
    {
      int rl = tid >> 2;
      int cq = (tid & 3) * 32;
      if (!tiledC) {
        size_t gb = (size_t)(bm * 128 + p * 64 + rl) * N + bn * 128 + cq;
#pragma unroll
        for (int j = 0; j < 4; j++)
          *(s16x8*)(C + gb + j * 8) = *(const s16x8*)&sm[rl * 136 + cq + j * 8];
      } else {
        const size_t tmBase = (size_t)(bm * 2 + p) * (N >> 6);
#pragma unroll
        for (int j = 0; j < 4; j++) {
          int col = bn * 128 + cq + j * 8;
          size_t addr = ((tmBase + (col >> 6)) << 12) + (rl << 6) + (col & 63);
          *(s16x8*)(C + addr) = *(const s16x8*)&sm[rl * 136 + cq + j * 8];
        }
      }
    }
    __syncthreads();
  }
}

// ---------------------------------------------------------------------------
// Fused-LN GEMM: x = LN(x + A@W + bias) * g + b. 64x256 tile, dbuf 80KB.
// r7 champion form (tiled A read). Used ONLY for out-proj (K=256). UNCHANGED.
// ---------------------------------------------------------------------------
#define LNHALF 20480   // u16 elems per buffer half (40KB)

__global__ __launch_bounds__(256, 2) void gemm_ln(
    int aOff, int wtOff, const void* bias, size_t bOff,
    const void* lng, const void* lnb, size_t lnOff, int K)
{
  const int f = g_f32flag;
  const u16* A = g_ws + aOff;
  const u16* Bt = g_wt + wtOff;
  __shared__ __align__(16) u16 sm[2 * LNHALF];   // 80KB: 2 x (A 8KB | B 32KB)
  const int tid = threadIdx.x;
  const int bm = blockIdx.x;                // 64-row tile
  const int lane = tid & 63, wid = tid >> 6;
  const int wn = wid * 64;
  const int frow = lane & 15, quad = lane >> 4;
  const int rg = lane >> 3;
  const int ck = ((lane & 7) ^ rg) * 8;

  // Tiled A: row-stripe bm holds K/64 tiles of 4096 elems, sequential in k.
  const u16* Ag[2]; u16* Asl[2];
  const u16* Bg[8]; u16* Bsl[8];
#pragma unroll
  for (int p = 0; p < 2; p++) {
    int grp = wid * 2 + p;                  // 0..8: rows 0..63
    Ag[p] = A + ((size_t)bm * (K >> 6) << 12) + ((grp * 8 + rg) << 6) + ck;
    Asl[p] = &sm[grp * 512];
  }
#pragma unroll
  for (int p = 0; p < 8; p++) {
    int grp = wid * 8 + p;                  // 0..32: Wt rows 0..255
    Bg[p] = Bt + (size_t)(grp * 8 + rg) * K + ck;
    Bsl[p] = &sm[4096 + grp * 512];
  }

  f32x4 acc[4][4] = {};
  const int nsteps = K >> 6;

  // Prologue: fill buffer 0 with K-tile 0.
#pragma unroll
  for (int p = 0; p < 2; p++) gload_lds16(Ag[p], Asl[p]);
#pragma unroll
  for (int p = 0; p < 8; p++) gload_lds16(Bg[p], Bsl[p]);
  __syncthreads();

  for (int t = 0; t < nsteps; t++) {
    const int cur = (t & 1) * LNHALF;
    if (t + 1 < nsteps) {
      const int nxt = ((t + 1) & 1) * LNHALF;
      const int ktA = (t + 1) << 12;        // tiled A: 4096 elems per K-tile
      const int ktB = (t + 1) << 6;         // row-major B: 64 elems per K-tile
#pragma unroll
      for (int p = 0; p < 2; p++) gload_lds16(Ag[p] + ktA, Asl[p] + nxt);
#pragma unroll
      for (int p = 0; p < 8; p++) gload_lds16(Bg[p] + ktB, Bsl[p] + nxt);
    }
#pragma unroll
    for (int s = 0; s < 2; s++) {
      s16x8 af[4], bfr[4];
      const int cfr = ((s * 4 + quad) ^ (frow & 7)) * 8;
#pragma unroll
      for (int ti = 0; ti < 4; ti++) {
        af[ti]  = *(const s16x8*)&sm[cur + (ti * 16 + frow) * 64 + cfr];
        bfr[ti] = *(const s16x8*)&sm[cur + 4096 + (wn + ti * 16 + frow) * 64 + cfr];
      }
#pragma unroll
      for (int mt = 0; mt < 4; mt++)
#pragma unroll
        for (int nt = 0; nt < 4; nt++)
          acc[mt][nt] = __builtin_amdgcn_mfma_f32_16x16x32_bf16(af[mt], bfr[nt], acc[mt][nt], 0, 0, 0);
    }
    __syncthreads();
  }

  // Epilogue.
  const int rl = tid >> 2;                 // row 0..63 (4 lanes per row)
  const int cq = (tid & 3) * 64;           // 64 cols per lane
  const size_t rowg = (size_t)bm * 64 + rl;
  s16x8 xr[8];
#pragma unroll
  for (int j = 0; j < 8; j++)
    xr[j] = *(const s16x8*)(g_ws + XOFF + rowg * 256 + cq + j * 8);

  float bv[4];
#pragma unroll
  for (int nt = 0; nt < 4; nt++)
    bv[nt] = ldf(bias, bOff + (size_t)(wn + nt * 16 + frow), f);
#pragma unroll
  for (int mt = 0; mt < 4; mt++)
#pragma unroll
    for (int nt = 0; nt < 4; nt++)
#pragma unroll
      for (int r = 0; r < 4; r++) {
        int row = mt * 16 + quad * 4 + r;
        int col = wn + nt * 16 + frow;
        sm[row * 264 + col] = f2b(acc[mt][nt][r] + bv[nt]);
      }
  __syncthreads();
  {
    float s1 = 0.f, s2 = 0.f;
#pragma unroll
    for (int j = 0; j < 8; j++) {
      s16x8 yv = *(const s16x8*)&sm[rl * 264 + cq + j * 8];
#pragma unroll
      for (int e = 0; e < 8; e++) {
        float v = b2f((u16)yv[e]) + b2f((u16)xr[j][e]);
        s1 += v; s2 += v * v;
      }
    }
    s1 += __shfl_xor(s1, 1, 64); s2 += __shfl_xor(s2, 1, 64);
    s1 += __shfl_xor(s1, 2, 64); s2 += __shfl_xor(s2, 2, 64);
    float mean = s1 * (1.f / 256.f);
    float var = s2 * (1.f / 256.f) - mean * mean;
    float rs = rsqrtf(var + 1e-5f);
#pragma unroll
    for (int j = 0; j < 8; j++) {
      s16x8 yv = *(const s16x8*)&sm[rl * 264 + cq + j * 8];
      s16x8 ov;
#pragma unroll
      for (int e = 0; e < 8; e++) {
        float v = b2f((u16)yv[e]) + b2f((u16)xr[j][e]);
        int col = cq + j * 8 + e;
        ov[e] = (short)f2b((v - mean) * rs * ldf(lng, lnOff + col, f) + ldf(lnb, lnOff + col, f));
      }
      *(s16x8*)(g_ws + XOFF + rowg * 256 + cq + j * 8) = ov;
    }
  }
}

// ---------------------------------------------------------------------------
// FUSED FFN v5 (resubmit; round-14 bench was an infra failure, no data):
// 2 barriers/chunk via W2 double-buffer. r13: champion reproduced (166us,
// MfmaUtil 19.7, HBM 13% — latency floor, not a HW roofline). Last untested
// sync lever: BARRIER COUNT. v4 added flight at 3 barriers/chunk (flat) but
// never cut the 48 round-trips/block. Change: W2 gets 2 buffers (LDS
// 100->132KB, still 1 block/CU => occupancy pinned, clean attribution);
// barC DELETED (48 -> 32 barriers/block):
//   barA: vmcnt(4)  [W1[c] oldest; W2[c] flies] -> ffn1 -> hs
//   barB: vmcnt(0)+lgkm  [only W2[c] outstanding; hs visible; W1 reads done]
//         -> issue W1[c+1] (W1S_) + W2[c+1] (other W2 buf) -> ffn2(w2cur)
// Safety: ffn2(c)'s hs/W2 ds_reads complete before their MFMAs (compiler
// lgkm waits), all pre-barA(c+1); hs rewritten only after barA(c+1);
// w2nxt last read at ffn2(c-1), >=2 s_barriers before overwrite at barB(c);
// queue order W1[c+1] < W2[c+1] keeps barA's vmcnt(4) exact.
// Same values / MFMA order / hs swizzle => absmax must stay 0.0234375.
// Falsifiers: absmax drift => revert champion. ffn>=160us => barrier count
// also not binding => serial-chain floor confirmed; hold champion, conclude.
// ---------------------------------------------------------------------------
#define XS3_ 0        // x kt3 slab:   8192 u16 (16KB)
#define W1S_ 8192     // W1 chunk:    16384 u16 (32KB), 4 kt-slabs of 4096
#define W2A_ 24576    // W2 buf A:    16384 u16 (32KB), 32 grps of 512
#define HS_  40960    // h tile:       8192 u16 (16KB), [128][64] XOR-swz
#define B1S_ 49152    // b1 staged:    2048 u16 (4KB) as 1024 f32
#define W2B_ 51200    // W2 buf B:    16384 u16 (32KB)
#define FFSM 67584    // total u16 (132KB); epilogue ybuf 33792 fits

__global__ __launch_bounds__(512, 2) void ffn_fused(
    int w1Off, const void* b1, size_t b1Off,
    int w2Off, const void* b2, size_t b2Off,
    const void* lng, const void* lnb, size_t lnOff)
{
  const int f = g_f32flag;
  const u16* W1t = g_wt + w1Off;   // [FF][256]
  const u16* W2t = g_wt + w2Off;   // [256][FF]
  __shared__ __align__(16) u16 sm[FFSM];
  const int tid = threadIdx.x;
  const int bm = blockIdx.x;            // 128-row stripe
  const int lane = tid & 63, wid = tid >> 6;
  const int frow = lane & 15, quad = lane >> 4;
  const int rg = lane >> 3;
  const int ck = ((lane & 7) ^ rg) * 8;
  const int wrow = (wid >> 2) * 64;     // row-half base (0 or 64)
  const int wcg = wid & 3;              // col-group 0..3

  // ---- Prologue: b1 -> LDS (exact f32); x tile -> LDS (4 kt slabs) ----
  {
    float* b1s = (float*)&sm[B1S_];
    b1s[tid * 2]     = ldf(b1, b1Off + tid * 2, f);
    b1s[tid * 2 + 1] = ldf(b1, b1Off + tid * 2 + 1, f);
  }
  {
    const u16* xg = g_ws + XOFF;
#pragma unroll
    for (int kt = 0; kt < 4; kt++) {
      const int dst = (kt == 0) ? W1S_ : (kt == 1) ? (W1S_ + 8192)
                    : (kt == 2) ? W2A_ : XS3_;
#pragma unroll
      for (int p = 0; p < 2; p++) {
        int grp = wid * 2 + p;          // 0..15: rows 0..127
        gload_lds16(xg + (size_t)(bm * 128 + grp * 8 + rg) * 256 + kt * 64 + ck,
                    &sm[dst + grp * 512]);
      }
    }
  }
  __builtin_amdgcn_sched_barrier(0);
  asm volatile("s_waitcnt vmcnt(0) lgkmcnt(0)" ::: "memory");
  __builtin_amdgcn_sched_barrier(0);
  __builtin_amdgcn_s_barrier();
  __builtin_amdgcn_sched_barrier(0);

  // ---- Hoist x fragments kt0..2 into registers (read LDS once) ----
  s16x8 xr[3][2][4];
#pragma unroll
  for (int kt = 0; kt < 3; kt++) {
    const int base = (kt == 0) ? W1S_ : (kt == 1) ? (W1S_ + 8192) : W2A_;
#pragma unroll
    for (int s = 0; s < 2; s++) {
      const int cfr = ((s * 4 + quad) ^ (frow & 7)) * 8;
#pragma unroll
      for (int mt = 0; mt < 4; mt++)
        xr[kt][s][mt] = *(const s16x8*)&sm[base + (wrow + mt * 16 + frow) * 64 + cfr];
    }
  }
  __builtin_amdgcn_sched_barrier(0);
  asm volatile("s_waitcnt lgkmcnt(0)" ::: "memory");
  __builtin_amdgcn_sched_barrier(0);
  __builtin_amdgcn_s_barrier();        // temp regions now free for W1/W2
  __builtin_amdgcn_sched_barrier(0);

  // Issue W1[0] (4 gloads) then W2[0] into buf A (4 gloads).
#pragma unroll
  for (int kt = 0; kt < 4; kt++)
    gload_lds16(W1t + (size_t)(wid * 8 + rg) * 256 + kt * 64 + ck,
                &sm[W1S_ + kt * 4096 + wid * 512]);
#pragma unroll
  for (int p = 0; p < 4; p++) {
    int grp = wid * 4 + p;
    gload_lds16(W2t + (size_t)(grp * 8 + rg) * 1024 + ck, &sm[W2A_ + grp * 512]);
  }

  f32x4 acc[4][4] = {};
  const float* b1s = (const float*)&sm[B1S_];

  for (int c = 0; c < 16; c++) {
    const int w2cur = (c & 1) ? W2B_ : W2A_;
    const int w2nxt = (c & 1) ? W2A_ : W2B_;
    // barA: W1[c] landed (oldest 4; W2[c] keeps flying).
    __builtin_amdgcn_sched_barrier(0);
    asm volatile("s_waitcnt vmcnt(4)" ::: "memory");
    __builtin_amdgcn_sched_barrier(0);
    __builtin_amdgcn_s_barrier();
    __builtin_amdgcn_sched_barrier(0);

    // ---- ffn1: h slice (rows wrow..+63, col wcg*16+frow) ----
    f32x4 a1[4] = {};
#pragma unroll
    for (int kt = 0; kt < 4; kt++)
#pragma unroll
      for (int s = 0; s < 2; s++) {
        const int cfr = ((s * 4 + quad) ^ (frow & 7)) * 8;
        s16x8 bf1 = *(const s16x8*)&sm[W1S_ + kt * 4096 + (wcg * 16 + frow) * 64 + cfr];
        if (kt < 3) {
#pragma unroll
          for (int mt = 0; mt < 4; mt++)
            a1[mt] = __builtin_amdgcn_mfma_f32_16x16x32_bf16(xr[kt][s][mt], bf1, a1[mt], 0, 0, 0);
        } else {
#pragma unroll
          for (int mt = 0; mt < 4; mt++) {
            s16x8 af = *(const s16x8*)&sm[XS3_ + (wrow + mt * 16 + frow) * 64 + cfr];
            a1[mt] = __builtin_amdgcn_mfma_f32_16x16x32_bf16(af, bf1, a1[mt], 0, 0, 0);
          }
        }
      }
    {
      float b1v = b1s[c * 64 + wcg * 16 + frow];   // broadcast within quad
#pragma unroll
      for (int mt = 0; mt < 4; mt++)
#pragma unroll
        for (int r = 0; r < 4; r++) {
          int row = wrow + mt * 16 + quad * 4 + r;
          int swz = (((wcg * 2 + (frow >> 3)) ^ ((quad * 4 + r) & 7)) << 3) + (frow & 7);
          sm[HS_ + row * 64 + swz] = f2b(fmaxf(a1[mt][r] + b1v, 0.f));
        }
    }
    // barB: W2[c] landed (only W2[c] outstanding); hs visible; W1 reads done.
    __builtin_amdgcn_sched_barrier(0);
    asm volatile("s_waitcnt vmcnt(0) lgkmcnt(0)" ::: "memory");
    __builtin_amdgcn_sched_barrier(0);
    __builtin_amdgcn_s_barrier();
    __builtin_amdgcn_sched_barrier(0);
    // Prefetch both W1[c+1] (W1 reads done pre-barB) and W2[c+1] (other
    // buffer; last read at ffn2(c-1), >=2 s_barriers ago). Queue order:
    // W1[c+1] (4) older than W2[c+1] (4) => next barA's vmcnt(4) exact.
    if (c + 1 < 16) {
#pragma unroll
      for (int kt = 0; kt < 4; kt++)
        gload_lds16(W1t + (size_t)((c + 1) * 64 + wid * 8 + rg) * 256 + kt * 64 + ck,
                    &sm[W1S_ + kt * 4096 + wid * 512]);
#pragma unroll
      for (int p = 0; p < 4; p++) {
        int grp = wid * 4 + p;
        gload_lds16(W2t + (size_t)(grp * 8 + rg) * 1024 + (c + 1) * 64 + ck,
                    &sm[w2nxt + grp * 512]);
      }
    }
    // ---- ffn2: acc += h_chunk @ W2chunk (reads w2cur) ----
#pragma unroll
    for (int s2 = 0; s2 < 2; s2++) {
      const int cfr = ((s2 * 4 + quad) ^ (frow & 7)) * 8;
      s16x8 ap[4], bf2[4];
#pragma unroll
      for (int ti = 0; ti < 4; ti++) {
        int row2 = wrow + ti * 16 + frow;
        int blk = (s2 * 4 + quad) ^ (frow & 7);
        ap[ti] = *(const s16x8*)&sm[HS_ + row2 * 64 + blk * 8];
      }
#pragma unroll
      for (int nt = 0; nt < 4; nt++)
        bf2[nt] = *(const s16x8*)&sm[w2cur + (wcg * 64 + nt * 16 + frow) * 64 + cfr];
#pragma unroll
      for (int mt = 0; mt < 4; mt++)
#pragma unroll
        for (int nt = 0; nt < 4; nt++)
          acc[mt][nt] = __builtin_amdgcn_mfma_f32_16x16x32_bf16(ap[mt], bf2[nt], acc[mt][nt], 0, 0, 0);
    }
    // no barC: hs reads complete before barA(c+1); hs writes are post-barA.
  }

  // Final barrier before epilogue reuses sm as ybuf (all ffn2 reads done).
  __syncthreads();

  // ---- Epilogue: x = LN(x + acc + b2). ybuf 128x264 reuses sm. ----
  const int rl = tid >> 2;                 // row 0..127 (4 lanes per row)
  const int cq = (tid & 3) * 64;           // 64 cols per lane
  const size_t rowg = (size_t)bm * 128 + rl;
  s16x8 resv[8];
#pragma unroll
  for (int j = 0; j < 8; j++)
    resv[j] = *(const s16x8*)(g_ws + XOFF + rowg * 256 + cq + j * 8);

  float bv[4];
#pragma unroll
  for (int nt = 0; nt < 4; nt++)
    bv[nt] = ldf(b2, b2Off + (size_t)(wcg * 64 + nt * 16 + frow), f);
#pragma unroll
  for (int mt = 0; mt < 4; mt++)
#pragma unroll
    for (int nt = 0; nt < 4; nt++)
#pragma unroll
      for (int r = 0; r < 4; r++) {
        int row = wrow + mt * 16 + quad * 4 + r;
        int col = wcg * 64 + nt * 16 + frow;
        sm[row * 264 + col] = f2b(acc[mt][nt][r] + bv[nt]);
      }
  __syncthreads();
  {
    float s1 = 0.f, s2 = 0.f;
#pragma unroll
    for (int j = 0; j < 8; j++) {
      s16x8 yv = *(const s16x8*)&sm[rl * 264 + cq + j * 8];
#pragma unroll
      for (int e = 0; e < 8; e++) {
        float v = b2f((u16)yv[e]) + b2f((u16)resv[j][e]);
        s1 += v; s2 += v * v;
      }
    }
    s1 += __shfl_xor(s1, 1, 64); s2 += __shfl_xor(s2, 1, 64);
    s1 += __shfl_xor(s1, 2, 64); s2 += __shfl_xor(s2, 2, 64);
    float mean = s1 * (1.f / 256.f);
    float var = s2 * (1.f / 256.f) - mean * mean;
    float rs = rsqrtf(var + 1e-5f);
#pragma unroll
    for (int j = 0; j < 8; j++) {
      s16x8 yv = *(const s16x8*)&sm[rl * 264 + cq + j * 8];
      s16x8 ov;
#pragma unroll
      for (int e = 0; e < 8; e++) {
        float v = b2f((u16)yv[e]) + b2f((u16)resv[j][e]);
        int col = cq + j * 8 + e;
        ov[e] = (short)f2b((v - mean) * rs * ldf(lng, lnOff + col, f) + ldf(lnb, lnOff + col, f));
      }
      *(s16x8*)(g_ws + XOFF + rowg * 256 + cq + j * 8) = ov;
    }
  }
}

// ---------------------------------------------------------------------------
// MFMA attention (S=151 padded 160). K staged via global_load_lds (KLD=32,
// xor-swizzle). Interleaved P-transpose; o written 64x64 tile-blocked
// (consumer: out-proj gemm_ln tiled-A read). r7 champion form, unchanged.
// ---------------------------------------------------------------------------
#define SP 160
#define KLD 32
#define VLD 170
#define PLDS 42

__global__ __launch_bounds__(320) void attn_kernel()
{
  const u16* qkv = g_ws + C1OFF;
  u16* o = g_ws + C2OFF;
  __shared__ __align__(16) u16 Ks[SP * KLD];        // 10240 B
  __shared__ __align__(16) u16 Vt[HD_ * VLD];       // 10880 B
  __shared__ __align__(16) u16 Ps[5][16 * PLDS];    // 6720 B
  int bh = blockIdx.x;
  int b = bh >> 3, h = bh & 7;
  int tid = threadIdx.x;
  int lane = tid & 63, wid = tid >> 6;
  const u16* base = qkv + (size_t)b * S_ * 768;

  // Stage K: global_load_lds, 2 groups of 16 rows per wave (xor-swizzled).
  {
    const int jrow = lane >> 2;
    const int dsw = (((lane & 3) ^ ((lane >> 3) & 3)) * 8);
#pragma unroll
    for (int p = 0; p < 2; p++) {
      int g = wid * 2 + p;                 // 0..9
      int j = g * 16 + jrow;               // 0..159; tail rows masked later
      gload_lds16(base + (size_t)j * 768 + 256 + h * 32 + dsw, &Ks[g * 512]);
    }
  }
  // Stage V transposed (zero-padded).
  for (int g = tid; g < SP * 4; g += 320) {
    int j = g >> 2, d0 = (g & 3) * 8;
    s16x8 vv = {0, 0, 0, 0, 0, 0, 0, 0};
    if (j < S_) vv = *(const s16x8*)(base + (size_t)j * 768 + 512 + h * 32 + d0);
#pragma unroll
    for (int i = 0; i < 8; i++) Vt[(d0 + i) * VLD + j] = (u16)vv[i];
  }
  __syncthreads();   // drains vmcnt (K gloads) + V writes

  const int frow = lane & 15;
  const int quad = lane >> 4;
  const int fk = quad * 8;
  const float scale = 0.17677669529663687f;  // 1/sqrt(32)
  u16* Pw = &Ps[wid][0];

  for (int round = 0; round < 2; round++) {
    int mt = round * 5 + wid;
    int qrow = mt * 16 + frow;
    s16x8 aq = {0, 0, 0, 0, 0, 0, 0, 0};
    if (qrow < S_) aq = *(const s16x8*)(base + (size_t)qrow * 768 + h * 32 + fk);
    f32x4 sacc[10];
#pragma unroll
    for (int nt = 0; nt < 10; nt++) {
      // un-swizzle: chunk quad lives at slot quad ^ ((row>>1)&3)
      s16x8 bk = *(const s16x8*)&Ks[(nt * 16 + frow) * KLD
                                    + ((quad ^ ((frow >> 1) & 3)) * 8)];
      f32x4 z = {0.f, 0.f, 0.f, 0.f};
      sacc[nt] = __builtin_amdgcn_mfma_f32_16x16x32_bf16(aq, bk, z, 0, 0, 0);
    }
#pragma unroll
    for (int nt = 0; nt < 10; nt++) {
      int colg = nt * 16 + frow;
      float msk = (colg < S_) ? 1.f : 0.f;
#pragma unroll
      for (int r = 0; r < 4; r++)
        sacc[nt][r] = msk ? sacc[nt][r] * scale : -1e30f;
    }
    float inv[4];
#pragma unroll
    for (int r = 0; r < 4; r++) {
      float mx = -1e30f;
#pragma unroll
      for (int nt = 0; nt < 10; nt++) mx = fmaxf(mx, sacc[nt][r]);
#pragma unroll
      for (int m = 1; m < 16; m <<= 1) mx = fmaxf(mx, __shfl_xor(mx, m, 64));
      float sm2 = 0.f;
#pragma unroll
      for (int nt = 0; nt < 10; nt++) {
        float p = __expf(sacc[nt][r] - mx);
        sacc[nt][r] = p;
        sm2 += p;
      }
#pragma unroll
      for (int m = 1; m < 16; m <<= 1) sm2 += __shfl_xor(sm2, m, 64);
      inv[r] = 1.f / sm2;
    }
    // Interleaved C->A transform + PV through wave-private buffer.
    f32x4 oacc[2] = {};
#pragma unroll
    for (int ks = 0; ks < 5; ks++) {
#pragma unroll
      for (int h2 = 0; h2 < 2; h2++) {
        int nt = ks * 2 + h2;
#pragma unroll
        for (int r = 0; r < 4; r++)
          Pw[(quad * 4 + r) * PLDS + h2 * 16 + frow] = f2b(sacc[nt][r]);
      }
      s16x8 ap = *(const s16x8*)&Pw[frow * PLDS + fk];
#pragma unroll
      for (int nt2 = 0; nt2 < 2; nt2++) {
        s16x8 bv = *(const s16x8*)&Vt[(nt2 * 16 + frow) * VLD + ks * 32 + fk];
        oacc[nt2] = __builtin_amdgcn_mfma_f32_16x16x32_bf16(ap, bv, oacc[nt2], 0, 0, 0);
      }
    }
#pragma unroll
    for (int nt2 = 0; nt2 < 2; nt2++)
#pragma unroll
      for (int r = 0; r < 4; r++) {
        int rowg = mt * 16 + quad * 4 + r;
        if (rowg < S_) {
          int gr = b * S_ + rowg;
          int gc = h * 32 + nt2 * 16 + frow;
          o[(((size_t)(gr >> 6) * (D_ >> 6) + (gc >> 6)) << 12)
            + ((gr & 63) << 6) + (gc & 63)] = f2b(oacc[nt2][r] * inv[r]);
        }
      }
  }
}

// ---------------------------------------------------------------------------
// Head: cls row -> two LNs (shared stats) -> two tiny matvecs.
// ---------------------------------------------------------------------------
__global__ __launch_bounds__(256) void head_kernel(
    const void* dg, const void* dbt, const void* dW, const void* dbias,
    const void* ag, const void* abt, const void* aW, const void* abias,
    void* out)
{
  const int f = g_f32flag;
  const u16* x = g_ws + XOFF;
  int bg = blockIdx.x;
  int tid = threadIdx.x;
  float c = b2f(x[(size_t)bg * S_ * D_ + tid]);
  float s1 = c, s2 = c * c;
#pragma unroll
  for (int off = 32; off > 0; off >>= 1) {
    s1 += __shfl_down(s1, off, 64);
    s2 += __shfl_down(s2, off, 64);
  }
  __shared__ float ws1[4], ws2[4], stats[2];
  __shared__ float lnD[256], lnA[256];
  int wid = tid >> 6, lane = tid & 63;
  if (lane == 0) { ws1[wid] = s1; ws2[wid] = s2; }
  __syncthreads();
  if (tid == 0) {
    float t1 = ws1[0] + ws1[1] + ws1[2] + ws1[3];
    float t2 = ws2[0] + ws2[1] + ws2[2] + ws2[3];
    float mean = t1 * (1.f / 256.f);
    float var = t2 * (1.f / 256.f) - mean * mean;
    stats[0] = mean;
    stats[1] = rsqrtf(var + 1e-5f);
  }
  __syncthreads();
  float n = (c - stats[0]) * stats[1];
  lnD[tid] = n * ldf(dg, tid, f) + ldf(dbt, tid, f);
  lnA[tid] = n * ldf(ag, tid, f) + ldf(abt, tid, f);
  __syncthreads();
  if (tid < NC_) {
    float acc = ldf(dbias, tid, f);
    for (int k = 0; k < D_; k++) acc += lnD[k] * ldf(dW, k * NC_ + tid, f);
    if (f) ((float*)out)[bg * NC_ + tid] = acc;
    else   ((bf16*)out)[bg * NC_ + tid] = __float2bfloat16(acc);
  } else if (tid == 8) {
    float acc = ldf(abias, 0, f);
    for (int k = 0; k < D_; k++) acc += lnA[k] * ldf(aW, k, f);
    if (f) ((float*)out)[B_ * NC_ + bg] = acc;
    else   ((bf16*)out)[B_ * NC_ + bg] = __float2bfloat16(acc);
  }
}

// ---------------------------------------------------------------------------
extern "C" void kernel_launch(void* const* d_in, const int* in_sizes, int n_in,
                              void* d_out, int out_size, void* d_ws, size_t ws_size,
                              hipStream_t stream)
{
  (void)in_sizes; (void)out_size; (void)d_ws; (void)ws_size;
  if (n_in < 34) return;
  const int* token_types  = (const int*)d_in[0];
  const int* decision_ids = (const int*)d_in[1];

  probe_kernel<<<1, 256, 0, stream>>>(d_in[12]);   // pos_embed

  wtrans_kernel<<<(DEPTH_ * D_ * 768 + 255) / 256, 256, 0, stream>>>(
      d_in[14], QKVT_OFF, D_, 768, DEPTH_ * D_ * 768);
  wtrans_kernel<<<(DEPTH_ * D_ * D_ + 255) / 256, 256, 0, stream>>>(
      d_in[16], OUTT_OFF, D_, D_, DEPTH_ * D_ * D_);
  wtrans_kernel<<<(DEPTH_ * D_ * FF_ + 255) / 256, 256, 0, stream>>>(
      d_in[22], FFN1T_OFF, D_, FF_, DEPTH_ * D_ * FF_);
  wtrans_kernel<<<(DEPTH_ * FF_ * D_ + 255) / 256, 256, 0, stream>>>(
      d_in[24], FFN2T_OFF, FF_, D_, DEPTH_ * FF_ * D_);

  embed_kernel<<<MTOT, 256, 0, stream>>>(token_types, decision_ids,
      d_in[2], d_in[3], d_in[4], d_in[5], d_in[6], d_in[7], d_in[8],
      d_in[9], d_in[10], d_in[11], d_in[12], d_in[13]);

  for (int i = 0; i < DEPTH_; i++) {
    gemm_mfma<<<6 * MT128, 256, 0, stream>>>(XOFF,
        QKVT_OFF + i * D_ * 768, d_in[15], (size_t)i * 768, C1OFF, 768, D_, 0, 6, 0);
    attn_kernel<<<B_ * H_, 320, 0, stream>>>();
    // out-proj fused: x = LN1(x + attn_out @ Wout + b); A (c2) tiled.
    gemm_ln<<<MT64, 256, 0, stream>>>(C2OFF,
        OUTT_OFF + i * D_ * D_, d_in[17], (size_t)i * D_,
        d_in[18], d_in[19], (size_t)i * D_, D_);
    // fused FFN v5: x = LN2(x + relu(x@W1+b1)@W2 + b2)
    ffn_fused<<<MT128, 512, 0, stream>>>(
        FFN1T_OFF + i * D_ * FF_, d_in[23], (size_t)i * FF_,
        FFN2T_OFF + i * FF_ * D_, d_in[25], (size_t)i * D_,
        d_in[20], d_in[21], (size_t)i * D_);
  }
  head_kernel<<<B_, 256, 0, stream>>>(d_in[26], d_in[27], d_in[28], d_in[29],
      d_in[30], d_in[31], d_in[32], d_in[33], d_out);
}

// Round 16
// 2365.582 us; speedup vs baseline: 1.0162x; 1.0162x over previous
//
#include <hip/hip_runtime.h>
#include <hip/hip_bf16.h>

typedef __hip_bfloat16 bf16;
typedef unsigned short u16;
typedef __attribute__((ext_vector_type(8))) short s16x8;   // 8 bf16 (4 VGPRs) MFMA frag
typedef __attribute__((ext_vector_type(4))) float f32x4;   // MFMA accumulator

#define B_ 512
#define T_ 150
#define S_ 151
#define D_ 256
#define H_ 8
#define HD_ 32
#define FF_ 1024
#define NC_ 4
#define DEPTH_ 6
#define MTOT 77312            // B_*S_ = 128 * 604 = 64 * 1208
#define MT128 (MTOT / 128)    // 604
#define MT64 (MTOT / 64)      // 1208

// bf16 workspace regions (elements):
#define XOFF 0
#define C1OFF (MTOT * D_)               // x: MTOT*256
#define C2OFF (C1OFF + MTOT * FF_)      // c1: MTOT*1024 (qkv out)
#define WSELEMS (C2OFF + MTOT * D_)     // c2: MTOT*256 (attn out, tiled)

// Transposed bf16 weights Wt[N][K], all layers, rebuilt per call:
#define QKVT_OFF 0
#define OUTT_OFF (QKVT_OFF + DEPTH_ * D_ * 768)
#define FFN1T_OFF (OUTT_OFF + DEPTH_ * D_ * D_)
#define FFN2T_OFF (FFN1T_OFF + DEPTH_ * D_ * FF_)
#define WTELEMS (FFN2T_OFF + DEPTH_ * FF_ * D_)    // 9.4 MB

// Static device memory (d_ws proved unusable rounds 1-3).
__device__ __align__(16) u16 g_ws[WSELEMS];
__device__ __align__(16) u16 g_wt[WTELEMS];
__device__ int g_f32flag;   // 1 => external buffers f32, 0 => bf16

__device__ __forceinline__ float ldf(const void* p, size_t i, int f) {
  return f ? ((const float*)p)[i] : __bfloat162float(((const bf16*)p)[i]);
}
__device__ __forceinline__ float b2f(u16 u) {
  union { unsigned int i; float f; } v; v.i = ((unsigned int)u) << 16; return v.f;
}
__device__ __forceinline__ u16 f2b(float x) {
  bf16 h = __float2bfloat16(x);
  return *reinterpret_cast<u16*>(&h);
}

// Async global->LDS, 16 B/lane. LDS dest = wave-uniform base + lane*16.
typedef __attribute__((address_space(3))) void lds_void;
typedef const __attribute__((address_space(1))) void glob_void;
__device__ __forceinline__ void gload_lds16(const u16* g, u16* l) {
  __builtin_amdgcn_global_load_lds((glob_void*)g, (lds_void*)l, 16, 0, 0);
}

// ---------------------------------------------------------------------------
// Dtype probe on pos_embed (38656 elems ~N(0,0.02^2)) viewed as 16-bit words.
// ---------------------------------------------------------------------------
#define PROBE_N 38656
__global__ __launch_bounds__(256) void probe_kernel(const void* pe)
{
  const u16* w = (const u16*)pe;
  int susp = 0, zeroEven = 0;
  for (int k = threadIdx.x; k < PROBE_N; k += 256) {
    u16 u = w[k];
    int ex = (u >> 7) & 0xFF;
    if (ex >= 141) susp++;
    if ((k & 1) == 0 && (u & 0x7FFF) == 0) zeroEven++;
  }
  __shared__ int s_susp, s_zero;
  if (threadIdx.x == 0) { s_susp = 0; s_zero = 0; }
  __syncthreads();
  atomicAdd(&s_susp, susp);
  atomicAdd(&s_zero, zeroEven);
  __syncthreads();
  if (threadIdx.x == 0)
    g_f32flag = (s_susp > 0 || s_zero >= ((PROBE_N / 2) * 9) / 10) ? 1 : 0;
}

// ---------------------------------------------------------------------------
// Weight transpose+convert: Wt[l][n][k] = W[l][k][n] as bf16.
// ---------------------------------------------------------------------------
__global__ __launch_bounds__(256) void wtrans_kernel(const void* src, int dstOff,
                                                     int K, int N, int total)
{
  const int f = g_f32flag;
  int idx = blockIdx.x * 256 + threadIdx.x;
  if (idx >= total) return;
  int kn = K * N;
  int l = idx / kn;
  int r = idx - l * kn;
  int k = r / N;
  int n = r - k * N;
  g_wt[dstOff + (size_t)l * kn + (size_t)n * K + k] = f2b(ldf(src, idx, f));
}

// ---------------------------------------------------------------------------
// Embedding: row = blockIdx.x, writes bf16 x.
// ---------------------------------------------------------------------------
__global__ __launch_bounds__(256) void embed_kernel(
    const int* __restrict__ tt, const int* __restrict__ dids,
    const void* av, const void* dv, const void* vv,
    const void* aW, const void* ab, const void* dW, const void* db,
    const void* vW, const void* vb, const void* table, const void* pos,
    const void* cls)
{
  const int f = g_f32flag;
  u16* x = g_ws + XOFF;
  int row = blockIdx.x;
  int d = threadIdx.x;
  int b = row / S_;
  int s = row - b * S_;
  float val;
  if (s == 0) {
    val = ldf(cls, d, f);
  } else {
    int t = s - 1;
    int idx = b * T_ + t;
    int ty = tt[idx];
    if (ty == 0) {
      val = ldf(av, idx, f) * ldf(aW, d, f) + ldf(ab, d, f);
    } else if (ty == 1) {
      float acc = ldf(db, d, f) + ldf(vb, d, f);
#pragma unroll
      for (int i = 0; i < 10; i++) acc += ldf(dv, (size_t)idx * 10 + i, f) * ldf(dW, i * D_ + d, f);
#pragma unroll
      for (int i = 0; i < 3; i++) acc += ldf(vv, (size_t)idx * 3 + i, f) * ldf(vW, i * D_ + d, f);
      val = acc;
    } else if (ty == 2) {
      int did = dids[idx] & (NC_ - 1);
      val = ldf(table, (size_t)did * D_ + d, f);
    } else {
      val = 0.f;
    }
  }
  val += ldf(pos, s * D_ + d, f);
  x[(size_t)row * D_ + d] = f2b(val);
}

// ---------------------------------------------------------------------------
// MFMA GEMM (round-9 proven): 128x128, BK=64, 256 thr, global_load_lds w=16,
// xor-swizzled chunks (0 conflicts), XCD swizzle, LDS-staged epilogue.
// Used for qkv only (tiledC=0). UNCHANGED.
// ---------------------------------------------------------------------------
__global__ __launch_bounds__(256, 3) void gemm_mfma(
    int aOff, int wtOff, const void* bias, size_t bOff,
    int cOff, int N, int K, int relu, int NB, int tiledC)
{
  const int f = g_f32flag;
  const u16* A = g_ws + aOff;
  const u16* Bt = g_wt + wtOff;
  u16* C = g_ws + cOff;
  __shared__ __align__(16) u16 sm[16384];
  const int tid = threadIdx.x;

  int gblk = blockIdx.x;
  int bm, bn;
  {
    const int full = (MT128 / 8) * 8;        // 600
    if (gblk < NB * full) {
      int per = NB * 8;
      int grp = gblk / per, rem = gblk % per;
      bm = grp * 8 + (rem & 7);
      bn = rem >> 3;
    } else {
      int id = gblk - NB * full;
      bm = full + id / NB;
      bn = id % NB;
    }
  }

  const int lane = tid & 63, wid = tid >> 6;
  const int wm = (wid >> 1) * 64, wn = (wid & 1) * 64;
  const int frow = lane & 15, quad = lane >> 4;

  const int rg = lane >> 3;
  const int ck = ((lane & 7) ^ rg) * 8;
  const u16* Ag[4]; const u16* Bg[4];
  u16 *Asl[4], *Bsl[4];
#pragma unroll
  for (int p = 0; p < 4; p++) {
    int grp = wid * 4 + p;
    int row = grp * 8 + rg;
    Ag[p] = A + (size_t)(bm * 128 + row) * K + ck;
    Bg[p] = Bt + (size_t)(bn * 128 + row) * K + ck;
    Asl[p] = &sm[grp * 512];
    Bsl[p] = &sm[8192 + grp * 512];
  }

  f32x4 acc[4][4] = {};

  for (int kt = 0; kt < K; kt += 64) {
    if (kt) __syncthreads();
#pragma unroll
    for (int p = 0; p < 4; p++) {
      gload_lds16(Ag[p] + kt, Asl[p]);
      gload_lds16(Bg[p] + kt, Bsl[p]);
    }
    __syncthreads();
#pragma unroll
    for (int s = 0; s < 2; s++) {
      s16x8 af[4], bfr[4];
      const int cfr = ((s * 4 + quad) ^ (frow & 7)) * 8;
#pragma unroll
      for (int t = 0; t < 4; t++) {
        af[t]  = *(const s16x8*)&sm[(wm + t * 16 + frow) * 64 + cfr];
        bfr[t] = *(const s16x8*)&sm[8192 + (wn + t * 16 + frow) * 64 + cfr];
      }
#pragma unroll
      for (int mt = 0; mt < 4; mt++)
#pragma unroll
        for (int nt = 0; nt < 4; nt++)
          acc[mt][nt] = __builtin_amdgcn_mfma_f32_16x16x32_bf16(af[mt], bfr[nt], acc[mt][nt], 0, 0, 0);
    }
  }

  float bv[4];
#pragma unroll
  for (int nt = 0; nt < 4; nt++)
    bv[nt] = ldf(bias, bOff + (size_t)(bn * 128 + wn + nt * 16 + frow), f);
  __syncthreads();
#pragma unroll
  for (int p = 0; p < 2; p++) {
    if ((wid >> 1) == p) {
#pragma unroll
      for (int mt = 0; mt < 4; mt++)
#pragma unroll
        for (int nt = 0; nt < 4; nt++)
#pragma unroll
          for (int r = 0; r < 4; r++) {
            int rl = (wm & 63) + mt * 16 + quad * 4 + r;
            float v = acc[mt][nt][r] + bv[nt];
            if (relu) v = fmaxf(v, 0.f);
            sm[rl * 136 + wn + nt * 16 + frow] = f2b(v);
          }
    }
    __syncthreads();
    {
      int rl = tid >> 2;
      int cq = (tid & 3) * 32;
      if (!tiledC) {
        size_t gb = (size_t)(bm * 128 + p * 64 + rl) * N + bn * 128 + cq;
#pragma unroll
        for (int j = 0; j < 4; j++)
          *(s16x8*)(C + gb + j * 8) = *(const s16x8*)&sm[rl * 136 + cq + j * 8];
      } else {
        const size_t tmBase = (size_t)(bm * 2 + p) * (N >> 6);
#pragma unroll
        for (int j = 0; j < 4; j++) {
          int col = bn * 128 + cq + j * 8;
          size_t addr = ((tmBase + (col >> 6)) << 12) + (rl << 6) + (col & 63);
          *(s16x8*)(C + addr) = *(const s16x8*)&sm[rl * 136 + cq + j * 8];
        }
      }
    }
    __syncthreads();
  }
}

// ---------------------------------------------------------------------------
// Fused-LN GEMM: x = LN(x + A@W + bias) * g + b. 64x256 tile, dbuf 80KB.
// r7 champion form (tiled A read). Used ONLY for out-proj (K=256). UNCHANGED.
// ---------------------------------------------------------------------------
#define LNHALF 20480   // u16 elems per buffer half (40KB)

__global__ __launch_bounds__(256, 2) void gemm_ln(
    int aOff, int wtOff, const void* bias, size_t bOff,
    const void* lng, const void* lnb, size_t lnOff, int K)
{
  const int f = g_f32flag;
  const u16* A = g_ws + aOff;
  const u16* Bt = g_wt + wtOff;
  __shared__ __align__(16) u16 sm[2 * LNHALF];   // 80KB: 2 x (A 8KB | B 32KB)
  const int tid = threadIdx.x;
  const int bm = blockIdx.x;                // 64-row tile
  const int lane = tid & 63, wid = tid >> 6;
  const int wn = wid * 64;
  const int frow = lane & 15, quad = lane >> 4;
  const int rg = lane >> 3;
  const int ck = ((lane & 7) ^ rg) * 8;

  // Tiled A: row-stripe bm holds K/64 tiles of 4096 elems, sequential in k.
  const u16* Ag[2]; u16* Asl[2];
  const u16* Bg[8]; u16* Bsl[8];
#pragma unroll
  for (int p = 0; p < 2; p++) {
    int grp = wid * 2 + p;                  // 0..8: rows 0..63
    Ag[p] = A + ((size_t)bm * (K >> 6) << 12) + ((grp * 8 + rg) << 6) + ck;
    Asl[p] = &sm[grp * 512];
  }
#pragma unroll
  for (int p = 0; p < 8; p++) {
    int grp = wid * 8 + p;                  // 0..32: Wt rows 0..255
    Bg[p] = Bt + (size_t)(grp * 8 + rg) * K + ck;
    Bsl[p] = &sm[4096 + grp * 512];
  }

  f32x4 acc[4][4] = {};
  const int nsteps = K >> 6;

  // Prologue: fill buffer 0 with K-tile 0.
#pragma unroll
  for (int p = 0; p < 2; p++) gload_lds16(Ag[p], Asl[p]);
#pragma unroll
  for (int p = 0; p < 8; p++) gload_lds16(Bg[p], Bsl[p]);
  __syncthreads();

  for (int t = 0; t < nsteps; t++) {
    const int cur = (t & 1) * LNHALF;
    if (t + 1 < nsteps) {
      const int nxt = ((t + 1) & 1) * LNHALF;
      const int ktA = (t + 1) << 12;        // tiled A: 4096 elems per K-tile
      const int ktB = (t + 1) << 6;         // row-major B: 64 elems per K-tile
#pragma unroll
      for (int p = 0; p < 2; p++) gload_lds16(Ag[p] + ktA, Asl[p] + nxt);
#pragma unroll
      for (int p = 0; p < 8; p++) gload_lds16(Bg[p] + ktB, Bsl[p] + nxt);
    }
#pragma unroll
    for (int s = 0; s < 2; s++) {
      s16x8 af[4], bfr[4];
      const int cfr = ((s * 4 + quad) ^ (frow & 7)) * 8;
#pragma unroll
      for (int ti = 0; ti < 4; ti++) {
        af[ti]  = *(const s16x8*)&sm[cur + (ti * 16 + frow) * 64 + cfr];
        bfr[ti] = *(const s16x8*)&sm[cur + 4096 + (wn + ti * 16 + frow) * 64 + cfr];
      }
#pragma unroll
      for (int mt = 0; mt < 4; mt++)
#pragma unroll
        for (int nt = 0; nt < 4; nt++)
          acc[mt][nt] = __builtin_amdgcn_mfma_f32_16x16x32_bf16(af[mt], bfr[nt], acc[mt][nt], 0, 0, 0);
    }
    __syncthreads();
  }

  // Epilogue.
  const int rl = tid >> 2;                 // row 0..63 (4 lanes per row)
  const int cq = (tid & 3) * 64;           // 64 cols per lane
  const size_t rowg = (size_t)bm * 64 + rl;
  s16x8 xr[8];
#pragma unroll
  for (int j = 0; j < 8; j++)
    xr[j] = *(const s16x8*)(g_ws + XOFF + rowg * 256 + cq + j * 8);

  float bv[4];
#pragma unroll
  for (int nt = 0; nt < 4; nt++)
    bv[nt] = ldf(bias, bOff + (size_t)(wn + nt * 16 + frow), f);
#pragma unroll
  for (int mt = 0; mt < 4; mt++)
#pragma unroll
    for (int nt = 0; nt < 4; nt++)
#pragma unroll
      for (int r = 0; r < 4; r++) {
        int row = mt * 16 + quad * 4 + r;
        int col = wn + nt * 16 + frow;
        sm[row * 264 + col] = f2b(acc[mt][nt][r] + bv[nt]);
      }
  __syncthreads();
  {
    float s1 = 0.f, s2 = 0.f;
#pragma unroll
    for (int j = 0; j < 8; j++) {
      s16x8 yv = *(const s16x8*)&sm[rl * 264 + cq + j * 8];
#pragma unroll
      for (int e = 0; e < 8; e++) {
        float v = b2f((u16)yv[e]) + b2f((u16)xr[j][e]);
        s1 += v; s2 += v * v;
      }
    }
    s1 += __shfl_xor(s1, 1, 64); s2 += __shfl_xor(s2, 1, 64);
    s1 += __shfl_xor(s1, 2, 64); s2 += __shfl_xor(s2, 2, 64);
    float mean = s1 * (1.f / 256.f);
    float var = s2 * (1.f / 256.f) - mean * mean;
    float rs = rsqrtf(var + 1e-5f);
#pragma unroll
    for (int j = 0; j < 8; j++) {
      s16x8 yv = *(const s16x8*)&sm[rl * 264 + cq + j * 8];
      s16x8 ov;
#pragma unroll
      for (int e = 0; e < 8; e++) {
        float v = b2f((u16)yv[e]) + b2f((u16)xr[j][e]);
        int col = cq + j * 8 + e;
        ov[e] = (short)f2b((v - mean) * rs * ldf(lng, lnOff + col, f) + ldf(lnb, lnOff + col, f));
      }
      *(s16x8*)(g_ws + XOFF + rowg * 256 + cq + j * 8) = ov;
    }
  }
}

// ---------------------------------------------------------------------------
// FUSED FFN v2 (FINAL CHAMPION, restored after v5 falsifier fired): x =
// LN2(x + relu(x@W1+b1)@W2 + b2), c1 never hits memory. 128-row stripe,
// 512 thr, 16 FF-chunks of 64, x kt0..2 hoisted to registers, hs stride-64
// XOR-swizzled, raw s_barrier + counted vmcnt, b1 pre-staged. Measured:
// 165.7-167us/dispatch; totals 2375.7 (r11) / 2377.8 (r13).
// Ablation matrix (all flat or negative): LDS reads -43% (r9), occupancy
// x2 (r10: conflicts), W1-dbuf full-flight (r12), barriers 48->32 (r15).
// The ~8us/chunk is the serial ffn1->hs->ffn2 chain at 1 block/CU — the
// decomposition's latency floor. Session: 2616 -> ~2376us (-9.2%) via
// r7 layout tiling + r8/r9 FFN fusion (c1 deleted, ~250MB/layer).
// ---------------------------------------------------------------------------
#define XS3_ 0        // x kt3 slab:   8192 u16 (16KB)
#define W1S_ 8192     // W1 chunk:    16384 u16 (32KB), 4 kt-slabs of 4096
#define W2S_ 24576    // W2 chunk:    16384 u16 (32KB), 32 grps of 512
#define HS_  40960    // h tile:       8192 u16 (16KB), [128][64] XOR-swz
#define B1S_ 49152    // b1 staged:    2048 u16 (4KB) as 1024 f32
#define FFSM 51200    // total u16 (100KB); epilogue ybuf 33792 fits

__global__ __launch_bounds__(512, 2) void ffn_fused(
    int w1Off, const void* b1, size_t b1Off,
    int w2Off, const void* b2, size_t b2Off,
    const void* lng, const void* lnb, size_t lnOff)
{
  const int f = g_f32flag;
  const u16* W1t = g_wt + w1Off;   // [FF][256]
  const u16* W2t = g_wt + w2Off;   // [256][FF]
  __shared__ __align__(16) u16 sm[FFSM];
  const int tid = threadIdx.x;
  const int bm = blockIdx.x;            // 128-row stripe
  const int lane = tid & 63, wid = tid >> 6;
  const int frow = lane & 15, quad = lane >> 4;
  const int rg = lane >> 3;
  const int ck = ((lane & 7) ^ rg) * 8;
  const int wrow = (wid >> 2) * 64;     // row-half base (0 or 64)
  const int wcg = wid & 3;              // col-group 0..3

  // ---- Prologue: b1 -> LDS (exact f32); x tile -> LDS (4 kt slabs) ----
  {
    float* b1s = (float*)&sm[B1S_];
    b1s[tid * 2]     = ldf(b1, b1Off + tid * 2, f);
    b1s[tid * 2 + 1] = ldf(b1, b1Off + tid * 2 + 1, f);
  }
  {
    const u16* xg = g_ws + XOFF;
#pragma unroll
    for (int kt = 0; kt < 4; kt++) {
      const int dst = (kt == 0) ? W1S_ : (kt == 1) ? (W1S_ + 8192)
                    : (kt == 2) ? W2S_ : XS3_;
#pragma unroll
      for (int p = 0; p < 2; p++) {
        int grp = wid * 2 + p;          // 0..15: rows 0..127
        gload_lds16(xg + (size_t)(bm * 128 + grp * 8 + rg) * 256 + kt * 64 + ck,
                    &sm[dst + grp * 512]);
      }
    }
  }
  __builtin_amdgcn_sched_barrier(0);
  asm volatile("s_waitcnt vmcnt(0) lgkmcnt(0)" ::: "memory");
  __builtin_amdgcn_sched_barrier(0);
  __builtin_amdgcn_s_barrier();
  __builtin_amdgcn_sched_barrier(0);

  // ---- Hoist x fragments kt0..2 into registers (read LDS once) ----
  s16x8 xr[3][2][4];
#pragma unroll
  for (int kt = 0; kt < 3; kt++) {
    const int base = (kt == 0) ? W1S_ : (kt == 1) ? (W1S_ + 8192) : W2S_;
#pragma unroll
    for (int s = 0; s < 2; s++) {
      const int cfr = ((s * 4 + quad) ^ (frow & 7)) * 8;
#pragma unroll
      for (int mt = 0; mt < 4; mt++)
        xr[kt][s][mt] = *(const s16x8*)&sm[base + (wrow + mt * 16 + frow) * 64 + cfr];
    }
  }
  __builtin_amdgcn_sched_barrier(0);
  asm volatile("s_waitcnt lgkmcnt(0)" ::: "memory");
  __builtin_amdgcn_sched_barrier(0);
  __builtin_amdgcn_s_barrier();        // xs regions now free for W1/W2
  __builtin_amdgcn_sched_barrier(0);

  // Issue W1[0] (4 gloads) then W2[0] (4 gloads).
#pragma unroll
  for (int kt = 0; kt < 4; kt++)
    gload_lds16(W1t + (size_t)(wid * 8 + rg) * 256 + kt * 64 + ck,
                &sm[W1S_ + kt * 4096 + wid * 512]);
#pragma unroll
  for (int p = 0; p < 4; p++) {
    int grp = wid * 4 + p;
    gload_lds16(W2t + (size_t)(grp * 8 + rg) * 1024 + ck, &sm[W2S_ + grp * 512]);
  }

  f32x4 acc[4][4] = {};
  const float* b1s = (const float*)&sm[B1S_];

  for (int c = 0; c < 16; c++) {
    // barA: W1[c] landed (4 newest = W2[c] may stay in flight).
    __builtin_amdgcn_sched_barrier(0);
    asm volatile("s_waitcnt vmcnt(4)" ::: "memory");
    __builtin_amdgcn_sched_barrier(0);
    __builtin_amdgcn_s_barrier();
    __builtin_amdgcn_sched_barrier(0);

    // ---- ffn1: h slice (rows wrow..+63, col wcg*16+frow) ----
    f32x4 a1[4] = {};
#pragma unroll
    for (int kt = 0; kt < 4; kt++)
#pragma unroll
      for (int s = 0; s < 2; s++) {
        const int cfr = ((s * 4 + quad) ^ (frow & 7)) * 8;
        s16x8 bf1 = *(const s16x8*)&sm[W1S_ + kt * 4096 + (wcg * 16 + frow) * 64 + cfr];
        if (kt < 3) {
#pragma unroll
          for (int mt = 0; mt < 4; mt++)
            a1[mt] = __builtin_amdgcn_mfma_f32_16x16x32_bf16(xr[kt][s][mt], bf1, a1[mt], 0, 0, 0);
        } else {
#pragma unroll
          for (int mt = 0; mt < 4; mt++) {
            s16x8 af = *(const s16x8*)&sm[XS3_ + (wrow + mt * 16 + frow) * 64 + cfr];
            a1[mt] = __builtin_amdgcn_mfma_f32_16x16x32_bf16(af, bf1, a1[mt], 0, 0, 0);
          }
        }
      }
    {
      float b1v = b1s[c * 64 + wcg * 16 + frow];   // broadcast within quad
#pragma unroll
      for (int mt = 0; mt < 4; mt++)
#pragma unroll
        for (int r = 0; r < 4; r++) {
          int row = wrow + mt * 16 + quad * 4 + r;
          int swz = (((wcg * 2 + (frow >> 3)) ^ ((quad * 4 + r) & 7)) << 3) + (frow & 7);
          sm[HS_ + row * 64 + swz] = f2b(fmaxf(a1[mt][r] + b1v, 0.f));
        }
    }
    // barB: hs visible; W1s(c) reads done; W2[c] landed (vmcnt 0).
    __builtin_amdgcn_sched_barrier(0);
    asm volatile("s_waitcnt vmcnt(0) lgkmcnt(0)" ::: "memory");
    __builtin_amdgcn_sched_barrier(0);
    __builtin_amdgcn_s_barrier();
    __builtin_amdgcn_sched_barrier(0);
    if (c + 1 < 16) {
#pragma unroll
      for (int kt = 0; kt < 4; kt++)
        gload_lds16(W1t + (size_t)((c + 1) * 64 + wid * 8 + rg) * 256 + kt * 64 + ck,
                    &sm[W1S_ + kt * 4096 + wid * 512]);
    }
    // ---- ffn2: acc += h_chunk @ W2chunk ----
#pragma unroll
    for (int s2 = 0; s2 < 2; s2++) {
      const int cfr = ((s2 * 4 + quad) ^ (frow & 7)) * 8;
      s16x8 ap[4], bf2[4];
#pragma unroll
      for (int ti = 0; ti < 4; ti++) {
        int row2 = wrow + ti * 16 + frow;
        int blk = (s2 * 4 + quad) ^ (frow & 7);
        ap[ti] = *(const s16x8*)&sm[HS_ + row2 * 64 + blk * 8];
      }
#pragma unroll
      for (int nt = 0; nt < 4; nt++)
        bf2[nt] = *(const s16x8*)&sm[W2S_ + (wcg * 64 + nt * 16 + frow) * 64 + cfr];
#pragma unroll
      for (int mt = 0; mt < 4; mt++)
#pragma unroll
        for (int nt = 0; nt < 4; nt++)
          acc[mt][nt] = __builtin_amdgcn_mfma_f32_16x16x32_bf16(ap[mt], bf2[nt], acc[mt][nt], 0, 0, 0);
    }
    // barC: hs + W2s(c) reads done (values materialized pre-barrier).
    __builtin_amdgcn_sched_barrier(0);
    __builtin_amdgcn_s_barrier();
    __builtin_amdgcn_sched_barrier(0);
    if (c + 1 < 16) {
#pragma unroll
      for (int p = 0; p < 4; p++) {
        int grp = wid * 4 + p;
        gload_lds16(W2t + (size_t)(grp * 8 + rg) * 1024 + (c + 1) * 64 + ck,
                    &sm[W2S_ + grp * 512]);
      }
    }
  }

  // ---- Epilogue: x = LN(x + acc + b2). ybuf 128x264 reuses sm. ----
  const int rl = tid >> 2;                 // row 0..127 (4 lanes per row)
  const int cq = (tid & 3) * 64;           // 64 cols per lane
  const size_t rowg = (size_t)bm * 128 + rl;
  s16x8 resv[8];
#pragma unroll
  for (int j = 0; j < 8; j++)
    resv[j] = *(const s16x8*)(g_ws + XOFF + rowg * 256 + cq + j * 8);

  float bv[4];
#pragma unroll
  for (int nt = 0; nt < 4; nt++)
    bv[nt] = ldf(b2, b2Off + (size_t)(wcg * 64 + nt * 16 + frow), f);
#pragma unroll
  for (int mt = 0; mt < 4; mt++)
#pragma unroll
    for (int nt = 0; nt < 4; nt++)
#pragma unroll
      for (int r = 0; r < 4; r++) {
        int row = wrow + mt * 16 + quad * 4 + r;
        int col = wcg * 64 + nt * 16 + frow;
        sm[row * 264 + col] = f2b(acc[mt][nt][r] + bv[nt]);
      }
  __syncthreads();
  {
    float s1 = 0.f, s2 = 0.f;
#pragma unroll
    for (int j = 0; j < 8; j++) {
      s16x8 yv = *(const s16x8*)&sm[rl * 264 + cq + j * 8];
#pragma unroll
      for (int e = 0; e < 8; e++) {
        float v = b2f((u16)yv[e]) + b2f((u16)resv[j][e]);
        s1 += v; s2 += v * v;
      }
    }
    s1 += __shfl_xor(s1, 1, 64); s2 += __shfl_xor(s2, 1, 64);
    s1 += __shfl_xor(s1, 2, 64); s2 += __shfl_xor(s2, 2, 64);
    float mean = s1 * (1.f / 256.f);
    float var = s2 * (1.f / 256.f) - mean * mean;
    float rs = rsqrtf(var + 1e-5f);
#pragma unroll
    for (int j = 0; j < 8; j++) {
      s16x8 yv = *(const s16x8*)&sm[rl * 264 + cq + j * 8];
      s16x8 ov;
#pragma unroll
      for (int e = 0; e < 8; e++) {
        float v = b2f((u16)yv[e]) + b2f((u16)resv[j][e]);
        int col = cq + j * 8 + e;
        ov[e] = (short)f2b((v - mean) * rs * ldf(lng, lnOff + col, f) + ldf(lnb, lnOff + col, f));
      }
      *(s16x8*)(g_ws + XOFF + rowg * 256 + cq + j * 8) = ov;
    }
  }
}

// ---------------------------------------------------------------------------
// MFMA attention (S=151 padded 160). K staged via global_load_lds (KLD=32,
// xor-swizzle). Interleaved P-transpose; o written 64x64 tile-blocked
// (consumer: out-proj gemm_ln tiled-A read). r7 champion form, unchanged.
// ---------------------------------------------------------------------------
#define SP 160
#define KLD 32
#define VLD 170
#define PLDS 42

__global__ __launch_bounds__(320) void attn_kernel()
{
  const u16* qkv = g_ws + C1OFF;
  u16* o = g_ws + C2OFF;
  __shared__ __align__(16) u16 Ks[SP * KLD];        // 10240 B
  __shared__ __align__(16) u16 Vt[HD_ * VLD];       // 10880 B
  __shared__ __align__(16) u16 Ps[5][16 * PLDS];    // 6720 B
  int bh = blockIdx.x;
  int b = bh >> 3, h = bh & 7;
  int tid = threadIdx.x;
  int lane = tid & 63, wid = tid >> 6;
  const u16* base = qkv + (size_t)b * S_ * 768;

  // Stage K: global_load_lds, 2 groups of 16 rows per wave (xor-swizzled).
  {
    const int jrow = lane >> 2;
    const int dsw = (((lane & 3) ^ ((lane >> 3) & 3)) * 8);
#pragma unroll
    for (int p = 0; p < 2; p++) {
      int g = wid * 2 + p;                 // 0..9
      int j = g * 16 + jrow;               // 0..159; tail rows masked later
      gload_lds16(base + (size_t)j * 768 + 256 + h * 32 + dsw, &Ks[g * 512]);
    }
  }
  // Stage V transposed (zero-padded).
  for (int g = tid; g < SP * 4; g += 320) {
    int j = g >> 2, d0 = (g & 3) * 8;
    s16x8 vv = {0, 0, 0, 0, 0, 0, 0, 0};
    if (j < S_) vv = *(const s16x8*)(base + (size_t)j * 768 + 512 + h * 32 + d0);
#pragma unroll
    for (int i = 0; i < 8; i++) Vt[(d0 + i) * VLD + j] = (u16)vv[i];
  }
  __syncthreads();   // drains vmcnt (K gloads) + V writes

  const int frow = lane & 15;
  const int quad = lane >> 4;
  const int fk = quad * 8;
  const float scale = 0.17677669529663687f;  // 1/sqrt(32)
  u16* Pw = &Ps[wid][0];

  for (int round = 0; round < 2; round++) {
    int mt = round * 5 + wid;
    int qrow = mt * 16 + frow;
    s16x8 aq = {0, 0, 0, 0, 0, 0, 0, 0};
    if (qrow < S_) aq = *(const s16x8*)(base + (size_t)qrow * 768 + h * 32 + fk);
    f32x4 sacc[10];
#pragma unroll
    for (int nt = 0; nt < 10; nt++) {
      // un-swizzle: chunk quad lives at slot quad ^ ((row>>1)&3)
      s16x8 bk = *(const s16x8*)&Ks[(nt * 16 + frow) * KLD
                                    + ((quad ^ ((frow >> 1) & 3)) * 8)];
      f32x4 z = {0.f, 0.f, 0.f, 0.f};
      sacc[nt] = __builtin_amdgcn_mfma_f32_16x16x32_bf16(aq, bk, z, 0, 0, 0);
    }
#pragma unroll
    for (int nt = 0; nt < 10; nt++) {
      int colg = nt * 16 + frow;
      float msk = (colg < S_) ? 1.f : 0.f;
#pragma unroll
      for (int r = 0; r < 4; r++)
        sacc[nt][r] = msk ? sacc[nt][r] * scale : -1e30f;
    }
    float inv[4];
#pragma unroll
    for (int r = 0; r < 4; r++) {
      float mx = -1e30f;
#pragma unroll
      for (int nt = 0; nt < 10; nt++) mx = fmaxf(mx, sacc[nt][r]);
#pragma unroll
      for (int m = 1; m < 16; m <<= 1) mx = fmaxf(mx, __shfl_xor(mx, m, 64));
      float sm2 = 0.f;
#pragma unroll
      for (int nt = 0; nt < 10; nt++) {
        float p = __expf(sacc[nt][r] - mx);
        sacc[nt][r] = p;
        sm2 += p;
      }
#pragma unroll
      for (int m = 1; m < 16; m <<= 1) sm2 += __shfl_xor(sm2, m, 64);
      inv[r] = 1.f / sm2;
    }
    // Interleaved C->A transform + PV through wave-private buffer.
    f32x4 oacc[2] = {};
#pragma unroll
    for (int ks = 0; ks < 5; ks++) {
#pragma unroll
      for (int h2 = 0; h2 < 2; h2++) {
        int nt = ks * 2 + h2;
#pragma unroll
        for (int r = 0; r < 4; r++)
          Pw[(quad * 4 + r) * PLDS + h2 * 16 + frow] = f2b(sacc[nt][r]);
      }
      s16x8 ap = *(const s16x8*)&Pw[frow * PLDS + fk];
#pragma unroll
      for (int nt2 = 0; nt2 < 2; nt2++) {
        s16x8 bv = *(const s16x8*)&Vt[(nt2 * 16 + frow) * VLD + ks * 32 + fk];
        oacc[nt2] = __builtin_amdgcn_mfma_f32_16x16x32_bf16(ap, bv, oacc[nt2], 0, 0, 0);
      }
    }
#pragma unroll
    for (int nt2 = 0; nt2 < 2; nt2++)
#pragma unroll
      for (int r = 0; r < 4; r++) {
        int rowg = mt * 16 + quad * 4 + r;
        if (rowg < S_) {
          int gr = b * S_ + rowg;
          int gc = h * 32 + nt2 * 16 + frow;
          o[(((size_t)(gr >> 6) * (D_ >> 6) + (gc >> 6)) << 12)
            + ((gr & 63) << 6) + (gc & 63)] = f2b(oacc[nt2][r] * inv[r]);
        }
      }
  }
}

// ---------------------------------------------------------------------------
// Head: cls row -> two LNs (shared stats) -> two tiny matvecs.
// ---------------------------------------------------------------------------
__global__ __launch_bounds__(256) void head_kernel(
    const void* dg, const void* dbt, const void* dW, const void* dbias,
    const void* ag, const void* abt, const void* aW, const void* abias,
    void* out)
{
  const int f = g_f32flag;
  const u16* x = g_ws + XOFF;
  int bg = blockIdx.x;
  int tid = threadIdx.x;
  float c = b2f(x[(size_t)bg * S_ * D_ + tid]);
  float s1 = c, s2 = c * c;
#pragma unroll
  for (int off = 32; off > 0; off >>= 1) {
    s1 += __shfl_down(s1, off, 64);
    s2 += __shfl_down(s2, off, 64);
  }
  __shared__ float ws1[4], ws2[4], stats[2];
  __shared__ float lnD[256], lnA[256];
  int wid = tid >> 6, lane = tid & 63;
  if (lane == 0) { ws1[wid] = s1; ws2[wid] = s2; }
  __syncthreads();
  if (tid == 0) {
    float t1 = ws1[0] + ws1[1] + ws1[2] + ws1[3];
    float t2 = ws2[0] + ws2[1] + ws2[2] + ws2[3];
    float mean = t1 * (1.f / 256.f);
    float var = t2 * (1.f / 256.f) - mean * mean;
    stats[0] = mean;
    stats[1] = rsqrtf(var + 1e-5f);
  }
  __syncthreads();
  float n = (c - stats[0]) * stats[1];
  lnD[tid] = n * ldf(dg, tid, f) + ldf(dbt, tid, f);
  lnA[tid] = n * ldf(ag, tid, f) + ldf(abt, tid, f);
  __syncthreads();
  if (tid < NC_) {
    float acc = ldf(dbias, tid, f);
    for (int k = 0; k < D_; k++) acc += lnD[k] * ldf(dW, k * NC_ + tid, f);
    if (f) ((float*)out)[bg * NC_ + tid] = acc;
    else   ((bf16*)out)[bg * NC_ + tid] = __float2bfloat16(acc);
  } else if (tid == 8) {
    float acc = ldf(abias, 0, f);
    for (int k = 0; k < D_; k++) acc += lnA[k] * ldf(aW, k, f);
    if (f) ((float*)out)[B_ * NC_ + bg] = acc;
    else   ((bf16*)out)[B_ * NC_ + bg] = __float2bfloat16(acc);
  }
}

// ---------------------------------------------------------------------------
extern "C" void kernel_launch(void* const* d_in, const int* in_sizes, int n_in,
                              void* d_out, int out_size, void* d_ws, size_t ws_size,
                              hipStream_t stream)
{
  (void)in_sizes; (void)out_size; (void)d_ws; (void)ws_size;
  if (n_in < 34) return;
  const int* token_types  = (const int*)d_in[0];
  const int* decision_ids = (const int*)d_in[1];

  probe_kernel<<<1, 256, 0, stream>>>(d_in[12]);   // pos_embed

  wtrans_kernel<<<(DEPTH_ * D_ * 768 + 255) / 256, 256, 0, stream>>>(
      d_in[14], QKVT_OFF, D_, 768, DEPTH_ * D_ * 768);
  wtrans_kernel<<<(DEPTH_ * D_ * D_ + 255) / 256, 256, 0, stream>>>(
      d_in[16], OUTT_OFF, D_, D_, DEPTH_ * D_ * D_);
  wtrans_kernel<<<(DEPTH_ * D_ * FF_ + 255) / 256, 256, 0, stream>>>(
      d_in[22], FFN1T_OFF, D_, FF_, DEPTH_ * D_ * FF_);
  wtrans_kernel<<<(DEPTH_ * FF_ * D_ + 255) / 256, 256, 0, stream>>>(
      d_in[24], FFN2T_OFF, FF_, D_, DEPTH_ * FF_ * D_);

  embed_kernel<<<MTOT, 256, 0, stream>>>(token_types, decision_ids,
      d_in[2], d_in[3], d_in[4], d_in[5], d_in[6], d_in[7], d_in[8],
      d_in[9], d_in[10], d_in[11], d_in[12], d_in[13]);

  for (int i = 0; i < DEPTH_; i++) {
    gemm_mfma<<<6 * MT128, 256, 0, stream>>>(XOFF,
        QKVT_OFF + i * D_ * 768, d_in[15], (size_t)i * 768, C1OFF, 768, D_, 0, 6, 0);
    attn_kernel<<<B_ * H_, 320, 0, stream>>>();
    // out-proj fused: x = LN1(x + attn_out @ Wout + b); A (c2) tiled.
    gemm_ln<<<MT64, 256, 0, stream>>>(C2OFF,
        OUTT_OFF + i * D_ * D_, d_in[17], (size_t)i * D_,
        d_in[18], d_in[19], (size_t)i * D_, D_);
    // fused FFN v2: x = LN2(x + relu(x@W1+b1)@W2 + b2)
    ffn_fused<<<MT128, 512, 0, stream>>>(
        FFN1T_OFF + i * D_ * FF_, d_in[23], (size_t)i * FF_,
        FFN2T_OFF + i * FF_ * D_, d_in[25], (size_t)i * D_,
        d_in[20], d_in[21], (size_t)i * D_);
  }
  head_kernel<<<B_, 256, 0, stream>>>(d_in[26], d_in[27], d_in[28], d_in[29],
      d_in[30], d_in[31], d_in[32], d_in[33], d_out);
}